// Round 8
// baseline (129.142 us; speedup 1.0000x reference)
//
#include <hip/hip_runtime.h>
#include <math.h>

#define DEV __device__ __forceinline__

typedef __attribute__((ext_vector_type(4))) float f32x4;
typedef __attribute__((ext_vector_type(8))) __bf16 bf16x8;

static constexpr int Bc = 2, Sc = 2048, Dc = 1024, Hc = 16, HDc = 64;
static constexpr int LDQ = 3 * Dc;                  // fused QKV row stride
static constexpr float SCL = 0.125f * 1.44269504f;  // 1/sqrt(64) * log2(e)

// f32 -> bf16 bits, round-to-nearest-even
DEV unsigned short f2b(float f) {
  union { float f; unsigned int u; } c; c.f = f;
  unsigned int u = c.u;
  unsigned int r = (u + 0x7fffu + ((u >> 16) & 1u)) >> 16;
  return (unsigned short)r;
}

// async global->LDS, 16B per lane; LDS dest = wave-uniform base + lane*16
DEV void async16(const void* g, void* l) {
  __builtin_amdgcn_global_load_lds(
      (__attribute__((address_space(1))) void*)(void*)g,
      (__attribute__((address_space(3))) void*)l, 16, 0, 0);
}

// XOR swizzle for [R][64] bf16 tiles (128B rows)
DEV int swz(int r, int c) { return r * 64 + (c ^ ((r & 7) << 3)); }

__global__ void cvt_x(const float* __restrict__ in,
                      unsigned short* __restrict__ out, int n4) {
  int i = blockIdx.x * blockDim.x + threadIdx.x;
  if (i < n4) {
    const float4 v = reinterpret_cast<const float4*>(in)[i];
    ushort4 o;
    o.x = f2b(v.x); o.y = f2b(v.y); o.z = f2b(v.z); o.w = f2b(v.w);
    reinterpret_cast<ushort4*>(out)[i] = o;
  }
}

// all four weight matrices in one launch; blockIdx.y selects the source
__global__ void cvt_w(const float* __restrict__ w0, const float* __restrict__ w1,
                      const float* __restrict__ w2, const float* __restrict__ w3,
                      unsigned short* __restrict__ out) {
  const float* src = blockIdx.y == 0 ? w0
                     : blockIdx.y == 1 ? w1
                     : blockIdx.y == 2 ? w2 : w3;
  const int i = blockIdx.x * blockDim.x + threadIdx.x;
  const float4 v = reinterpret_cast<const float4*>(src)[i];
  ushort4 o;
  o.x = f2b(v.x); o.y = f2b(v.y); o.z = f2b(v.z); o.w = f2b(v.w);
  reinterpret_cast<ushort4*>(out)[(size_t)blockIdx.y * (Dc * Dc / 4) + i] = o;
}

// C[M][*] = A[M][K] * Bm[*][K]^T + bias; bias selected per 1024-col group.
// 1D grid with bijective XCD-chunk swizzle (gridDim.x % 8 == 0); M = 4096.
template <typename OUT>
__global__ __launch_bounds__(256, 3) void gemm_bt(
    const unsigned short* __restrict__ A, const unsigned short* __restrict__ Bm,
    const float* __restrict__ b0, const float* __restrict__ b1,
    const float* __restrict__ b2, OUT* __restrict__ C, int M, int K, int ldc) {
  __shared__ unsigned short As[128 * 64];
  __shared__ unsigned short Bs[128 * 64];
  const int tid = threadIdx.x;
  const int wave = tid >> 6, lane = tid & 63;
  const int wr = wave >> 1, wc = wave & 1;
  // XCD swizzle: each XCD gets a contiguous chunk of column-major tile order
  const int cpx = gridDim.x >> 3;
  const int swzid = (blockIdx.x & 7) * cpx + (blockIdx.x >> 3);
  const int row0 = (swzid & 31) * 128, col0 = (swzid >> 5) * 128;
  const int srow = lane >> 3, scol = (lane & 7) * 8;

  f32x4 acc[4][4];
#pragma unroll
  for (int m = 0; m < 4; ++m)
#pragma unroll
    for (int n = 0; n < 4; ++n) acc[m][n] = {0.f, 0.f, 0.f, 0.f};

  for (int k0 = 0; k0 < K; k0 += 64) {
    __syncthreads();
#pragma unroll
    for (int c = 0; c < 4; ++c) {
      const int rr = (wave * 4 + c) * 8 + srow;
      async16(A + (size_t)(row0 + rr) * K + k0 + scol,
              (char*)As + (wave * 4 + c) * 1024);
      async16(Bm + (size_t)(col0 + rr) * K + k0 + scol,
              (char*)Bs + (wave * 4 + c) * 1024);
    }
    __syncthreads();
#pragma unroll
    for (int ks = 0; ks < 2; ++ks) {
      const int kk = ks * 32 + (lane >> 4) * 8;
      bf16x8 af[4], bfr[4];
#pragma unroll
      for (int m = 0; m < 4; ++m)
        af[m] = *reinterpret_cast<const bf16x8*>(
            &As[(wr * 64 + m * 16 + (lane & 15)) * 64 + kk]);
#pragma unroll
      for (int n = 0; n < 4; ++n)
        bfr[n] = *reinterpret_cast<const bf16x8*>(
            &Bs[(wc * 64 + n * 16 + (lane & 15)) * 64 + kk]);
#pragma unroll
      for (int m = 0; m < 4; ++m)
#pragma unroll
        for (int n = 0; n < 4; ++n)
          acc[m][n] = __builtin_amdgcn_mfma_f32_16x16x32_bf16(af[m], bfr[n],
                                                              acc[m][n], 0, 0, 0);
    }
  }
  const int r4 = (lane >> 4) * 4, cl = lane & 15;
#pragma unroll
  for (int n = 0; n < 4; ++n) {
    const int gc = col0 + wc * 64 + n * 16 + cl;
    const float* bp = gc < Dc ? b0 : (gc < 2 * Dc ? b1 : b2);
    const float bv = bp[gc & (Dc - 1)];
#pragma unroll
    for (int m = 0; m < 4; ++m) {
#pragma unroll
      for (int j = 0; j < 4; ++j) {
        const int gr = row0 + wr * 64 + m * 16 + r4 + j;
        const float v = acc[m][n][j] + bv;
        if constexpr (sizeof(OUT) == 4)
          C[(size_t)gr * ldc + gc] = v;
        else
          C[(size_t)gr * ldc + gc] = (OUT)f2b(v);
      }
    }
  }
}

// flash attention, 2-phase pipelined, flash-decoding split-K:
//   qb 8..31: two k-chunks per q-tile (each <=16 tiles) -> partials (OP, ML)
//   qb 0..7 : single chunk, writes Og directly
// grid 1792 > resident slots (1024) -> hardware backfill; heavy-first order.
__global__ __launch_bounds__(256, 4) void attn_fwd(
    const __bf16* __restrict__ Qg, const __bf16* __restrict__ Kg,
    const __bf16* __restrict__ Vg, const int* __restrict__ kpm,
    __bf16* __restrict__ Og, __bf16* __restrict__ OP,
    float* __restrict__ ML) {
  __shared__ __bf16 QP[64 * 64];     // Q tile, reused as per-wave P tiles
  __shared__ __bf16 Ks[2][64 * 64];  // double-buffered K
  __shared__ __bf16 Vt[2][64 * 64];  // double-buffered V^T [d][k]

  // work decode, heavy-first: ids 0..1535 = split chunks (qb 31..8),
  // ids 1536..1791 = unsplit (qb 7..0)
  const int L = blockIdx.x;
  int bh, qb, kb0, kb1, pidx;
  bool split;
  if (L < 1536) {
    qb = 31 - (L >> 6);
    const int chunk = (L >> 5) & 1;
    bh = L & 31;
    const int c0 = (qb + 1) >> 1;
    kb0 = chunk ? c0 : 0;
    kb1 = chunk ? qb : c0 - 1;
    split = true;
    pidx = (bh * 24 + (qb - 8)) * 2 + chunk;
  } else {
    const int b2 = L - 1536;
    qb = 7 - (b2 >> 5);
    bh = b2 & 31;
    kb0 = 0; kb1 = qb;
    split = false;
    pidx = 0;
  }

  const int b = bh >> 4, h = bh & 15;
  const int q0 = qb * 64;
  const int k00 = kb0 * 64;
  const int tid = threadIdx.x, wave = tid >> 6, lane = tid & 63;
  const size_t base = (size_t)b * Sc * LDQ + (size_t)h * HDc;
  const int srow = lane >> 3;
  const int scol = 8 * ((lane & 7) ^ srow);  // inverse-swizzled source col
  const int hi = lane >> 4, cl = lane & 15, r4 = hi * 4;

  // V loader: 2 k-rows x 8 d per thread; packed b32 swizzled writes
  const int vk2 = (tid & 31) * 2, vd8 = (tid >> 5) * 8;
  const __bf16* vbase = Vg + base + (size_t)vk2 * LDQ + vd8;
  const int* mbase = kpm + b * Sc;

  union VV { uint4 q; unsigned short u[8]; };

  // prologue: stage Q + K@kb0 (async), V@kb0 + mask (regs)
#pragma unroll
  for (int cc = 0; cc < 2; ++cc) {
    const int rr = (wave * 2 + cc) * 8 + srow;
    async16(Qg + base + (size_t)(q0 + rr) * LDQ + scol,
            (char*)QP + (wave * 2 + cc) * 1024);
    async16(Kg + base + (size_t)(k00 + rr) * LDQ + scol,
            (char*)Ks[0] + (wave * 2 + cc) * 1024);
  }
  VV v0, v1;
  v0.q = *reinterpret_cast<const uint4*>(vbase + (size_t)k00 * LDQ);
  v1.q = *reinterpret_cast<const uint4*>(vbase + (size_t)(k00 + 1) * LDQ);
  int mki[4];
#pragma unroll
  for (int n = 0; n < 4; ++n) mki[n] = mbase[k00 + n * 16 + cl];
  {
    unsigned int* V32 = reinterpret_cast<unsigned int*>(Vt[0]);
#pragma unroll
    for (int i = 0; i < 8; ++i) {
      const int row = vd8 + i;
      V32[row * 32 + ((tid & 31) ^ ((row & 7) << 2))] =
          (unsigned int)v0.u[i] | ((unsigned int)v1.u[i] << 16);
    }
  }
  __syncthreads();

  bf16x8 qf[2];
#pragma unroll
  for (int ks = 0; ks < 2; ++ks)
    qf[ks] = *reinterpret_cast<const bf16x8*>(
        &QP[swz(wave * 16 + cl, ks * 32 + hi * 8)]);
  __bf16* Ps = QP + wave * 1024;  // per-wave 16x64 P tile

  bf16x8 ones;
#pragma unroll
  for (int i = 0; i < 8; ++i) ones[i] = (__bf16)1.0f;

  f32x4 o[4], lacc;
  float m_[4];
#pragma unroll
  for (int n = 0; n < 4; ++n) o[n] = {0.f, 0.f, 0.f, 0.f};
  lacc = {0.f, 0.f, 0.f, 0.f};
#pragma unroll
  for (int j = 0; j < 4; ++j) m_[j] = -1e30f;

  int pb = 0;
  for (int kb = kb0; kb <= kb1; ++kb) {
    const bool last = (kb == kb1);  // last staged tile of this chunk
    const bool diag = (kb == qb);   // diagonal tile (chunk2/unsplit only)
    VV n0, n1;
    int nmk[4];
    if (!last) {  // issue next tile's stage FIRST (hides under compute)
      const int k1 = (kb + 1) * 64;
#pragma unroll
      for (int cc = 0; cc < 2; ++cc) {
        const int rr = (wave * 2 + cc) * 8 + srow;
        async16(Kg + base + (size_t)(k1 + rr) * LDQ + scol,
                (char*)Ks[pb ^ 1] + (wave * 2 + cc) * 1024);
      }
      n0.q = *reinterpret_cast<const uint4*>(vbase + (size_t)k1 * LDQ);
      n1.q = *reinterpret_cast<const uint4*>(vbase + (size_t)(k1 + 1) * LDQ);
#pragma unroll
      for (int n = 0; n < 4; ++n) nmk[n] = mbase[k1 + n * 16 + cl];
    }

    // S = Q K^T from Ks[pb]
    f32x4 sa[4];
#pragma unroll
    for (int n = 0; n < 4; ++n) sa[n] = {0.f, 0.f, 0.f, 0.f};
    __builtin_amdgcn_s_setprio(1);
#pragma unroll
    for (int ks = 0; ks < 2; ++ks) {
      const int kk = ks * 32 + hi * 8;
#pragma unroll
      for (int n = 0; n < 4; ++n) {
        if (!(diag && n > wave)) {  // frags fully above diagonal: skip
          const bf16x8 kf = *reinterpret_cast<const bf16x8*>(
              &Ks[pb][swz(n * 16 + cl, kk)]);
          sa[n] = __builtin_amdgcn_mfma_f32_16x16x32_bf16(qf[ks], kf, sa[n],
                                                          0, 0, 0);
        }
      }
    }
    __builtin_amdgcn_s_setprio(0);
    // scale (base-2) + pad mask + causal (diag only) + partial max
    float pm[4] = {-1e30f, -1e30f, -1e30f, -1e30f};
#pragma unroll
    for (int n = 0; n < 4; ++n) {
      const float mf = mki[n] ? -1e30f : 0.0f;
#pragma unroll
      for (int j = 0; j < 4; ++j) {
        float s2 = fmaf(sa[n][j], SCL, mf);
        if (diag && (kb * 64 + n * 16 + cl > q0 + wave * 16 + r4 + j))
          s2 = -1e30f;
        sa[n][j] = s2;
        pm[j] = fmaxf(pm[j], s2);
      }
    }
    // defer-max: rescale only when some row grew by > 8 (base-2 units)
    const bool ok = (pm[0] - m_[0] <= 8.f) && (pm[1] - m_[1] <= 8.f) &&
                    (pm[2] - m_[2] <= 8.f) && (pm[3] - m_[3] <= 8.f);
    if (!__all(ok)) {
#pragma unroll
      for (int off = 1; off < 16; off <<= 1)
#pragma unroll
        for (int j = 0; j < 4; ++j)
          pm[j] = fmaxf(pm[j], __shfl_xor(pm[j], off, 64));
#pragma unroll
      for (int j = 0; j < 4; ++j) {
        const float mn = fmaxf(m_[j], pm[j]);
        const float sc = __builtin_amdgcn_exp2f(m_[j] - mn);
        m_[j] = mn;
        lacc[j] *= sc;
#pragma unroll
        for (int n = 0; n < 4; ++n) o[n][j] *= sc;
      }
    }
    // P = 2^(s2 - m) -> per-wave LDS tile
#pragma unroll
    for (int n = 0; n < 4; ++n)
#pragma unroll
      for (int j = 0; j < 4; ++j) {
        const float p = __builtin_amdgcn_exp2f(sa[n][j] - m_[j]);
        Ps[swz(r4 + j, n * 16 + cl)] = (__bf16)p;
      }
    // O += P V ; l += P * 1
    __builtin_amdgcn_s_setprio(1);
#pragma unroll
    for (int ks = 0; ks < 2; ++ks) {
      const int kk = ks * 32 + hi * 8;
      const bf16x8 pf = *reinterpret_cast<const bf16x8*>(&Ps[swz(cl, kk)]);
#pragma unroll
      for (int n = 0; n < 4; ++n) {
        const bf16x8 vf = *reinterpret_cast<const bf16x8*>(
            &Vt[pb][swz(n * 16 + cl, kk)]);
        o[n] = __builtin_amdgcn_mfma_f32_16x16x32_bf16(pf, vf, o[n], 0, 0, 0);
      }
      lacc = __builtin_amdgcn_mfma_f32_16x16x32_bf16(pf, ones, lacc, 0, 0, 0);
    }
    __builtin_amdgcn_s_setprio(0);
    // write next V (loads had the whole tile to land) + rotate mask
    if (!last) {
      unsigned int* V32 = reinterpret_cast<unsigned int*>(Vt[pb ^ 1]);
#pragma unroll
      for (int i = 0; i < 8; ++i) {
        const int row = vd8 + i;
        V32[row * 32 + ((tid & 31) ^ ((row & 7) << 2))] =
            (unsigned int)n0.u[i] | ((unsigned int)n1.u[i] << 16);
      }
#pragma unroll
      for (int n = 0; n < 4; ++n) mki[n] = nmk[n];
    }
    __syncthreads();  // drains K-async (vmcnt) + V ds_writes (lgkm)
    pb ^= 1;
  }

  if (!split) {  // normalize and write final output
#pragma unroll
    for (int j = 0; j < 4; ++j) {
      const float inv = 1.f / lacc[j];
#pragma unroll
      for (int n = 0; n < 4; ++n)
        Og[(size_t)(b * Sc + q0 + wave * 16 + r4 + j) * Dc + h * HDc + n * 16 +
           cl] = (__bf16)(o[n][j] * inv);
    }
  } else {  // unnormalized partial + per-row (m, l)
    __bf16* op = OP + (size_t)pidx * 4096;
    float* ml = ML + (size_t)pidx * 128;
#pragma unroll
    for (int j = 0; j < 4; ++j) {
      const int row = wave * 16 + r4 + j;
      if (cl == 0) {
        ml[row * 2 + 0] = m_[j];
        ml[row * 2 + 1] = lacc[j];
      }
#pragma unroll
      for (int n = 0; n < 4; ++n) op[row * 64 + n * 16 + cl] = (__bf16)o[n][j];
    }
  }
}

// merge the two partial chunks for qb 8..31
__global__ __launch_bounds__(256) void attn_combine(
    const __bf16* __restrict__ OP, const float* __restrict__ ML,
    __bf16* __restrict__ Og) {
  const int qq = blockIdx.x;   // 0..23 -> qb = 8+qq
  const int bh = blockIdx.y;   // 0..31
  const int qb = 8 + qq;
  const int b = bh >> 4, h = bh & 15;
  const int t = threadIdx.x;
  const int row = t >> 2, c0 = (t & 3) * 16;
  const int p0 = (bh * 24 + qq) * 2;
  const __bf16* o1 = OP + (size_t)p0 * 4096 + row * 64 + c0;
  const __bf16* o2 = OP + (size_t)(p0 + 1) * 4096 + row * 64 + c0;
  const float m1 = ML[(size_t)p0 * 128 + row * 2];
  const float l1 = ML[(size_t)p0 * 128 + row * 2 + 1];
  const float m2 = ML[(size_t)(p0 + 1) * 128 + row * 2];
  const float l2 = ML[(size_t)(p0 + 1) * 128 + row * 2 + 1];
  const float m = fmaxf(m1, m2);
  const float s1 = __builtin_amdgcn_exp2f(m1 - m);
  const float s2 = __builtin_amdgcn_exp2f(m2 - m);
  const float inv = 1.f / (l1 * s1 + l2 * s2);
  const bf16x8 a0 = *reinterpret_cast<const bf16x8*>(o1);
  const bf16x8 a1 = *reinterpret_cast<const bf16x8*>(o1 + 8);
  const bf16x8 b0 = *reinterpret_cast<const bf16x8*>(o2);
  const bf16x8 b1 = *reinterpret_cast<const bf16x8*>(o2 + 8);
  bf16x8 r0, r1;
#pragma unroll
  for (int i = 0; i < 8; ++i) {
    r0[i] = (__bf16)(((float)a0[i] * s1 + (float)b0[i] * s2) * inv);
    r1[i] = (__bf16)(((float)a1[i] * s1 + (float)b1[i] * s2) * inv);
  }
  __bf16* dst = Og + (size_t)(b * Sc + qb * 64 + row) * Dc + h * HDc + c0;
  *reinterpret_cast<bf16x8*>(dst) = r0;
  *reinterpret_cast<bf16x8*>(dst + 8) = r1;
}

extern "C" void kernel_launch(void* const* d_in, const int* in_sizes, int n_in,
                              void* d_out, int out_size, void* d_ws,
                              size_t ws_size, hipStream_t stream) {
  const float* X = (const float*)d_in[0];
  const int* kpm = (const int*)d_in[1];
  const float* Wq = (const float*)d_in[2];
  const float* bq = (const float*)d_in[3];
  const float* Wk = (const float*)d_in[4];
  const float* bk = (const float*)d_in[5];
  const float* Wv = (const float*)d_in[6];
  const float* bv = (const float*)d_in[7];
  const float* Wo = (const float*)d_in[8];
  const float* bo = (const float*)d_in[9];
  float* out = (float*)d_out;

  char* w = (char*)d_ws;
  unsigned short* Xb = (unsigned short*)(w);                  // 8 MB
  unsigned short* Wqkvb = (unsigned short*)(w + (8u << 20));  // 6 MB (q,k,v)
  unsigned short* Wob = (unsigned short*)(w + (14u << 20));   // 2 MB
  unsigned short* QKVb = (unsigned short*)(w + (16u << 20));  // 24 MB
  unsigned short* Ab = (unsigned short*)(w + (40u << 20));    // 8 MB -> 48 MB
  // attn partials overlay the (dead-after-QKV-GEMM) Xb/Wqkvb region:
  __bf16* OP = (__bf16*)(w);                       // 1536*4096*2 = 12.6 MB
  float* ML = (float*)(w + 12'582'912);            // 1536*128*4  = 0.8 MB

  const int MD = Bc * Sc;  // 4096
  cvt_x<<<dim3(MD * Dc / 1024), 256, 0, stream>>>(X, Xb, MD * Dc / 4);
  cvt_w<<<dim3(Dc * Dc / 1024, 4), 256, 0, stream>>>(Wq, Wk, Wv, Wo, Wqkvb);

  // fused QKV projection: C is [4096][3072]; 768 blocks (96/XCD)
  gemm_bt<unsigned short><<<dim3(32 * 24), 256, 0, stream>>>(
      Xb, Wqkvb, bq, bk, bv, QKVb, MD, Dc, LDQ);

  attn_fwd<<<dim3(1792), 256, 0, stream>>>(
      (const __bf16*)QKVb, (const __bf16*)QKVb + Dc,
      (const __bf16*)QKVb + 2 * Dc, kpm, (__bf16*)Ab, OP, ML);
  attn_combine<<<dim3(24, 32), 256, 0, stream>>>(OP, ML, (__bf16*)Ab);

  // output projection: 256 blocks (32/XCD)
  gemm_bt<float><<<dim3(32 * 8), 256, 0, stream>>>(
      Ab, Wob, bo, bo, bo, out, MD, Dc, Dc);
}

// Round 9
// 125.126 us; speedup vs baseline: 1.0321x; 1.0321x over previous
//
#include <hip/hip_runtime.h>
#include <math.h>

#define DEV __device__ __forceinline__

typedef __attribute__((ext_vector_type(4))) float f32x4;
typedef __attribute__((ext_vector_type(8))) __bf16 bf16x8;

static constexpr int Bc = 2, Sc = 2048, Dc = 1024, Hc = 16, HDc = 64;
static constexpr int LDQ = 3 * Dc;                  // fused QKV row stride
static constexpr float SCL = 0.125f * 1.44269504f;  // 1/sqrt(64) * log2(e)

// f32 -> bf16 bits, round-to-nearest-even
DEV unsigned short f2b(float f) {
  union { float f; unsigned int u; } c; c.f = f;
  unsigned int u = c.u;
  unsigned int r = (u + 0x7fffu + ((u >> 16) & 1u)) >> 16;
  return (unsigned short)r;
}

// async global->LDS, 16B per lane; LDS dest = wave-uniform base + lane*16
DEV void async16(const void* g, void* l) {
  __builtin_amdgcn_global_load_lds(
      (__attribute__((address_space(1))) void*)(void*)g,
      (__attribute__((address_space(3))) void*)l, 16, 0, 0);
}

// XOR swizzle for [R][64] bf16 tiles (128B rows)
DEV int swz(int r, int c) { return r * 64 + (c ^ ((r & 7) << 3)); }

// one launch converts X and all four weight matrices to bf16
__global__ void cvt_all(const float* __restrict__ X, const float* __restrict__ Wq,
                        const float* __restrict__ Wk, const float* __restrict__ Wv,
                        const float* __restrict__ Wo,
                        unsigned short* __restrict__ Xb,
                        unsigned short* __restrict__ Wb) {
  const int i = blockIdx.x * blockDim.x + threadIdx.x;  // float4 index
  const float* src;
  unsigned short* dst;
  int o;
  if (i < (1 << 20)) {  // X: 2^20 float4
    src = X; o = i; dst = Xb;
  } else {
    const int wi = i - (1 << 20);
    const int m = wi >> 18;  // 2^18 float4 per weight matrix
    src = m == 0 ? Wq : m == 1 ? Wk : m == 2 ? Wv : Wo;
    o = wi & ((1 << 18) - 1);
    dst = Wb + (size_t)m * (Dc * Dc);
  }
  const float4 v = reinterpret_cast<const float4*>(src)[o];
  ushort4 u;
  u.x = f2b(v.x); u.y = f2b(v.y); u.z = f2b(v.z); u.w = f2b(v.w);
  reinterpret_cast<ushort4*>(dst)[o] = u;
}

// ---------------------------------------------------------------------------
// 256x256-tile 8-wave GEMM, BK=64, double-buffered LDS (128 KB), counted-vmcnt
// pipeline (never drains to 0 mid-loop), T2 XOR-swizzle, T5 setprio.
// C[M][ldc] = A[M][K] * Bm[*][K]^T + bias (per-1024-col group). OUT = bf16.
// Schedule per K-tile kt (buf d = kt&1): entry{vmcnt(4); s_barrier}; 4 phases:
//   P0: issue A-half0[kt+1] (other buf) ; 16 MFMA (M-frags 0,1)
//   P1: issue A-half1[kt+1]             ; 16 MFMA (2,3)
//   --- s_barrier (B[kt] fully consumed at iteration top) ---
//   P2: issue B-half0[kt+2] (same buf)  ; 16 MFMA (4,5)
//   P3: issue B-half1[kt+2]             ; 16 MFMA (6,7)
// In-flight ledger: entry holds {B0,B1,A0,A1}[kt] + {B0,B1}[kt+1] = 12 loads;
// vmcnt(4) drains tile kt, leaves B[kt+1] (4). Tail: vmcnt(0) at kt==L.
__global__ __launch_bounds__(512, 2) void gemm256(
    const unsigned short* __restrict__ A, const unsigned short* __restrict__ Bm,
    const float* __restrict__ b0, const float* __restrict__ b1,
    const float* __restrict__ b2, unsigned short* __restrict__ C, int K,
    int ldc) {
  __shared__ unsigned short As2[2][256 * 64];  // 64 KB
  __shared__ unsigned short Bs2[2][256 * 64];  // 64 KB
  const int tid = threadIdx.x;
  const int wave = tid >> 6, lane = tid & 63;
  const int wr = wave >> 2, wc = wave & 3;  // 2x4 wave grid
  const int hi = lane >> 4, cl = lane & 15;
  const int L = K / 64 - 1;

  // XCD-chunk swizzle over 192 blocks (16 row-tiles x 12 col-tiles)
  const int cpx = gridDim.x >> 3;
  const int id = (blockIdx.x & 7) * cpx + (blockIdx.x >> 3);
  const int row0 = (id / 12) * 256, col0 = (id % 12) * 256;

  // staging geometry: 512 threads x 16B = 8 KB/round; half-tile = 16 KB
  const int trow = tid >> 3;                        // 0..63
  const int scolw = 8 * ((tid & 7) ^ (trow & 7));   // inverse-swizzled col
  const unsigned short* Abase = A + (size_t)(row0 + trow) * K + scolw;
  const unsigned short* Bbase = Bm + (size_t)(col0 + trow) * K + scolw;

  auto stA = [&](int kt, int h) {
#pragma unroll
    for (int c = 0; c < 2; ++c)
      async16(Abase + (size_t)(h * 128 + c * 64) * K + kt * 64,
              (char*)&As2[kt & 1][(h * 128 + c * 64 + wave * 8) * 64] +
                  lane * 16);
  };
  auto stB = [&](int kt, int h) {
#pragma unroll
    for (int c = 0; c < 2; ++c)
      async16(Bbase + (size_t)(h * 128 + c * 64) * K + kt * 64,
              (char*)&Bs2[kt & 1][(h * 128 + c * 64 + wave * 8) * 64] +
                  lane * 16);
  };

  f32x4 acc[8][4];
#pragma unroll
  for (int m = 0; m < 8; ++m)
#pragma unroll
    for (int n = 0; n < 4; ++n) acc[m][n] = {0.f, 0.f, 0.f, 0.f};

  // prologue stream (order defines the vmcnt ledger):
  stB(0, 0); stB(0, 1); stA(0, 0); stA(0, 1); stB(1, 0); stB(1, 1);

  for (int kt = 0; kt <= L; ++kt) {
    const int d = kt & 1;
    if (kt < L)
      asm volatile("s_waitcnt vmcnt(4)" ::: "memory");
    else
      asm volatile("s_waitcnt vmcnt(0)" ::: "memory");
    __builtin_amdgcn_s_barrier();
    __builtin_amdgcn_sched_barrier(0);

    // B-fragments for the whole iteration (8 x ds_read_b128)
    bf16x8 bfr[4][2];
#pragma unroll
    for (int n = 0; n < 4; ++n)
#pragma unroll
      for (int ks = 0; ks < 2; ++ks)
        bfr[n][ks] = *reinterpret_cast<const bf16x8*>(
            &Bs2[d][swz(wc * 64 + n * 16 + cl, ks * 32 + hi * 8)]);

#pragma unroll
    for (int p = 0; p < 4; ++p) {
      if (p == 2) {
        __builtin_amdgcn_s_barrier();  // B[kt] consumed; B-slots reusable
        __builtin_amdgcn_sched_barrier(0);
      }
      if (p == 0 && kt < L) stA(kt + 1, 0);
      if (p == 1 && kt < L) stA(kt + 1, 1);
      if (p == 2 && kt < L - 1) stB(kt + 2, 0);
      if (p == 3 && kt < L - 1) stB(kt + 2, 1);

      bf16x8 af[2][2];
#pragma unroll
      for (int mf = 0; mf < 2; ++mf)
#pragma unroll
        for (int ks = 0; ks < 2; ++ks)
          af[mf][ks] = *reinterpret_cast<const bf16x8*>(
              &As2[d][swz(wr * 128 + p * 32 + mf * 16 + cl,
                          ks * 32 + hi * 8)]);
      __builtin_amdgcn_s_setprio(1);
#pragma unroll
      for (int mf = 0; mf < 2; ++mf)
#pragma unroll
        for (int n = 0; n < 4; ++n)
#pragma unroll
          for (int ks = 0; ks < 2; ++ks)
            acc[p * 2 + mf][n] = __builtin_amdgcn_mfma_f32_16x16x32_bf16(
                af[mf][ks], bfr[n][ks], acc[p * 2 + mf][n], 0, 0, 0);
      __builtin_amdgcn_s_setprio(0);
    }
  }

  // epilogue: bias + bf16 store
#pragma unroll
  for (int n = 0; n < 4; ++n) {
    const int gc = col0 + wc * 64 + n * 16 + cl;
    const float* bp = gc < Dc ? b0 : (gc < 2 * Dc ? b1 : b2);
    const float bv = bp[gc & (Dc - 1)];
#pragma unroll
    for (int m = 0; m < 8; ++m) {
#pragma unroll
      for (int j = 0; j < 4; ++j) {
        const int gr = row0 + wr * 128 + m * 16 + hi * 4 + j;
        C[(size_t)gr * ldc + gc] = f2b(acc[m][n][j] + bv);
      }
    }
  }
}

// C[M][*] = A[M][K] * Bm[*][K]^T + bias (128x128 tile) — output projection
template <typename OUT>
__global__ __launch_bounds__(256, 3) void gemm_bt(
    const unsigned short* __restrict__ A, const unsigned short* __restrict__ Bm,
    const float* __restrict__ b0, const float* __restrict__ b1,
    const float* __restrict__ b2, OUT* __restrict__ C, int M, int K, int ldc) {
  __shared__ unsigned short As[128 * 64];
  __shared__ unsigned short Bs[128 * 64];
  const int tid = threadIdx.x;
  const int wave = tid >> 6, lane = tid & 63;
  const int wr = wave >> 1, wc = wave & 1;
  const int cpx = gridDim.x >> 3;
  const int swzid = (blockIdx.x & 7) * cpx + (blockIdx.x >> 3);
  const int row0 = (swzid & 31) * 128, col0 = (swzid >> 5) * 128;
  const int srow = lane >> 3, scol = (lane & 7) * 8;

  f32x4 acc[4][4];
#pragma unroll
  for (int m = 0; m < 4; ++m)
#pragma unroll
    for (int n = 0; n < 4; ++n) acc[m][n] = {0.f, 0.f, 0.f, 0.f};

  for (int k0 = 0; k0 < K; k0 += 64) {
    __syncthreads();
#pragma unroll
    for (int c = 0; c < 4; ++c) {
      const int rr = (wave * 4 + c) * 8 + srow;
      async16(A + (size_t)(row0 + rr) * K + k0 + scol,
              (char*)As + (wave * 4 + c) * 1024);
      async16(Bm + (size_t)(col0 + rr) * K + k0 + scol,
              (char*)Bs + (wave * 4 + c) * 1024);
    }
    __syncthreads();
#pragma unroll
    for (int ks = 0; ks < 2; ++ks) {
      const int kk = ks * 32 + (lane >> 4) * 8;
      bf16x8 af[4], bfr[4];
#pragma unroll
      for (int m = 0; m < 4; ++m)
        af[m] = *reinterpret_cast<const bf16x8*>(
            &As[(wr * 64 + m * 16 + (lane & 15)) * 64 + kk]);
#pragma unroll
      for (int n = 0; n < 4; ++n)
        bfr[n] = *reinterpret_cast<const bf16x8*>(
            &Bs[(wc * 64 + n * 16 + (lane & 15)) * 64 + kk]);
#pragma unroll
      for (int m = 0; m < 4; ++m)
#pragma unroll
        for (int n = 0; n < 4; ++n)
          acc[m][n] = __builtin_amdgcn_mfma_f32_16x16x32_bf16(af[m], bfr[n],
                                                              acc[m][n], 0, 0, 0);
    }
  }
  const int r4 = (lane >> 4) * 4, cl = lane & 15;
#pragma unroll
  for (int n = 0; n < 4; ++n) {
    const int gc = col0 + wc * 64 + n * 16 + cl;
    const float* bp = gc < Dc ? b0 : (gc < 2 * Dc ? b1 : b2);
    const float bv = bp[gc & (Dc - 1)];
#pragma unroll
    for (int m = 0; m < 4; ++m) {
#pragma unroll
      for (int j = 0; j < 4; ++j) {
        const int gr = row0 + wr * 64 + m * 16 + r4 + j;
        const float v = acc[m][n][j] + bv;
        if constexpr (sizeof(OUT) == 4)
          C[(size_t)gr * ldc + gc] = v;
        else
          C[(size_t)gr * ldc + gc] = (OUT)f2b(v);
      }
    }
  }
}

// flash attention, 2-phase pipelined (proven R5/R7 structure + balanced map)
__global__ __launch_bounds__(256, 4) void attn_fwd(
    const __bf16* __restrict__ Qg, const __bf16* __restrict__ Kg,
    const __bf16* __restrict__ Vg, const int* __restrict__ kpm,
    __bf16* __restrict__ Og) {
  __shared__ __bf16 QP[64 * 64];     // Q tile, reused as per-wave P tiles
  __shared__ __bf16 Ks[2][64 * 64];  // double-buffered K
  __shared__ __bf16 Vt[2][64 * 64];  // double-buffered V^T [d][k]

  // balanced work mapping: L = s*256 + c; slots on one CU sum qb to 62
  const int L = blockIdx.x;
  const int s = L >> 8, c = L & 255;
  const int u = c >> 5, bh = c & 31;
  const int qb = s * 8 + ((s & 1) ? (7 - u) : u);

  const int b = bh >> 4, h = bh & 15;
  const int q0 = qb * 64;
  const int tid = threadIdx.x, wave = tid >> 6, lane = tid & 63;
  const size_t base = (size_t)b * Sc * LDQ + (size_t)h * HDc;
  const int srow = lane >> 3;
  const int scol = 8 * ((lane & 7) ^ srow);  // inverse-swizzled source col
  const int hi = lane >> 4, cl = lane & 15, r4 = hi * 4;

  // V loader: 2 k-rows x 8 d per thread; packed b32 swizzled writes
  const int vk2 = (tid & 31) * 2, vd8 = (tid >> 5) * 8;
  const __bf16* vbase = Vg + base + (size_t)vk2 * LDQ + vd8;
  const int* mbase = kpm + b * Sc;

  union VV { uint4 q; unsigned short u[8]; };

  // prologue: stage Q + K0 (async), V0 + mask0 (regs)
#pragma unroll
  for (int cc = 0; cc < 2; ++cc) {
    const int rr = (wave * 2 + cc) * 8 + srow;
    async16(Qg + base + (size_t)(q0 + rr) * LDQ + scol,
            (char*)QP + (wave * 2 + cc) * 1024);
    async16(Kg + base + (size_t)rr * LDQ + scol,
            (char*)Ks[0] + (wave * 2 + cc) * 1024);
  }
  VV v0, v1;
  v0.q = *reinterpret_cast<const uint4*>(vbase);
  v1.q = *reinterpret_cast<const uint4*>(vbase + LDQ);
  int mki[4];
#pragma unroll
  for (int n = 0; n < 4; ++n) mki[n] = mbase[n * 16 + cl];
  {
    unsigned int* V32 = reinterpret_cast<unsigned int*>(Vt[0]);
#pragma unroll
    for (int i = 0; i < 8; ++i) {
      const int row = vd8 + i;
      V32[row * 32 + ((tid & 31) ^ ((row & 7) << 2))] =
          (unsigned int)v0.u[i] | ((unsigned int)v1.u[i] << 16);
    }
  }
  __syncthreads();

  bf16x8 qf[2];
#pragma unroll
  for (int ks = 0; ks < 2; ++ks)
    qf[ks] = *reinterpret_cast<const bf16x8*>(
        &QP[swz(wave * 16 + cl, ks * 32 + hi * 8)]);
  __bf16* Ps = QP + wave * 1024;  // per-wave 16x64 P tile

  bf16x8 ones;
#pragma unroll
  for (int i = 0; i < 8; ++i) ones[i] = (__bf16)1.0f;

  f32x4 o[4], lacc;
  float m_[4];
#pragma unroll
  for (int n = 0; n < 4; ++n) o[n] = {0.f, 0.f, 0.f, 0.f};
  lacc = {0.f, 0.f, 0.f, 0.f};
#pragma unroll
  for (int j = 0; j < 4; ++j) m_[j] = -1e30f;

  int pb = 0;
  for (int kb = 0; kb <= qb; ++kb) {
    const bool diag = (kb == qb);  // last tile is the diagonal tile
    VV n0, n1;
    int nmk[4];
    if (!diag) {  // issue next tile's stage FIRST (hides under compute)
      const int k1 = (kb + 1) * 64;
#pragma unroll
      for (int cc = 0; cc < 2; ++cc) {
        const int rr = (wave * 2 + cc) * 8 + srow;
        async16(Kg + base + (size_t)(k1 + rr) * LDQ + scol,
                (char*)Ks[pb ^ 1] + (wave * 2 + cc) * 1024);
      }
      n0.q = *reinterpret_cast<const uint4*>(vbase + (size_t)k1 * LDQ);
      n1.q = *reinterpret_cast<const uint4*>(vbase + (size_t)(k1 + 1) * LDQ);
#pragma unroll
      for (int n = 0; n < 4; ++n) nmk[n] = mbase[k1 + n * 16 + cl];
    }

    // S = Q K^T from Ks[pb]
    f32x4 sa[4];
#pragma unroll
    for (int n = 0; n < 4; ++n) sa[n] = {0.f, 0.f, 0.f, 0.f};
    __builtin_amdgcn_s_setprio(1);
#pragma unroll
    for (int ks = 0; ks < 2; ++ks) {
      const int kk = ks * 32 + hi * 8;
#pragma unroll
      for (int n = 0; n < 4; ++n) {
        if (!(diag && n > wave)) {  // frags fully above diagonal: skip
          const bf16x8 kf = *reinterpret_cast<const bf16x8*>(
              &Ks[pb][swz(n * 16 + cl, kk)]);
          sa[n] = __builtin_amdgcn_mfma_f32_16x16x32_bf16(qf[ks], kf, sa[n],
                                                          0, 0, 0);
        }
      }
    }
    __builtin_amdgcn_s_setprio(0);
    // scale (base-2) + pad mask + causal (diag only) + partial max
    float pm[4] = {-1e30f, -1e30f, -1e30f, -1e30f};
#pragma unroll
    for (int n = 0; n < 4; ++n) {
      const float mf = mki[n] ? -1e30f : 0.0f;
#pragma unroll
      for (int j = 0; j < 4; ++j) {
        float s2 = fmaf(sa[n][j], SCL, mf);
        if (diag && (kb * 64 + n * 16 + cl > q0 + wave * 16 + r4 + j))
          s2 = -1e30f;
        sa[n][j] = s2;
        pm[j] = fmaxf(pm[j], s2);
      }
    }
    // defer-max: rescale only when some row grew by > 8 (base-2 units)
    const bool ok = (pm[0] - m_[0] <= 8.f) && (pm[1] - m_[1] <= 8.f) &&
                    (pm[2] - m_[2] <= 8.f) && (pm[3] - m_[3] <= 8.f);
    if (!__all(ok)) {
#pragma unroll
      for (int off = 1; off < 16; off <<= 1)
#pragma unroll
        for (int j = 0; j < 4; ++j)
          pm[j] = fmaxf(pm[j], __shfl_xor(pm[j], off, 64));
#pragma unroll
      for (int j = 0; j < 4; ++j) {
        const float mn = fmaxf(m_[j], pm[j]);
        const float sc = __builtin_amdgcn_exp2f(m_[j] - mn);
        m_[j] = mn;
        lacc[j] *= sc;
#pragma unroll
        for (int n = 0; n < 4; ++n) o[n][j] *= sc;
      }
    }
    // P = 2^(s2 - m) -> per-wave LDS tile
#pragma unroll
    for (int n = 0; n < 4; ++n)
#pragma unroll
      for (int j = 0; j < 4; ++j) {
        const float p = __builtin_amdgcn_exp2f(sa[n][j] - m_[j]);
        Ps[swz(r4 + j, n * 16 + cl)] = (__bf16)p;
      }
    // O += P V ; l += P * 1
    __builtin_amdgcn_s_setprio(1);
#pragma unroll
    for (int ks = 0; ks < 2; ++ks) {
      const int kk = ks * 32 + hi * 8;
      const bf16x8 pf = *reinterpret_cast<const bf16x8*>(&Ps[swz(cl, kk)]);
#pragma unroll
      for (int n = 0; n < 4; ++n) {
        const bf16x8 vf = *reinterpret_cast<const bf16x8*>(
            &Vt[pb][swz(n * 16 + cl, kk)]);
        o[n] = __builtin_amdgcn_mfma_f32_16x16x32_bf16(pf, vf, o[n], 0, 0, 0);
      }
      lacc = __builtin_amdgcn_mfma_f32_16x16x32_bf16(pf, ones, lacc, 0, 0, 0);
    }
    __builtin_amdgcn_s_setprio(0);
    // write next V (loads had the whole tile to land) + rotate mask
    if (!diag) {
      unsigned int* V32 = reinterpret_cast<unsigned int*>(Vt[pb ^ 1]);
#pragma unroll
      for (int i = 0; i < 8; ++i) {
        const int row = vd8 + i;
        V32[row * 32 + ((tid & 31) ^ ((row & 7) << 2))] =
            (unsigned int)n0.u[i] | ((unsigned int)n1.u[i] << 16);
      }
#pragma unroll
      for (int n = 0; n < 4; ++n) mki[n] = nmk[n];
    }
    __syncthreads();  // drains K-async (vmcnt) + V ds_writes (lgkm)
    pb ^= 1;
  }

#pragma unroll
  for (int j = 0; j < 4; ++j) {
    const float inv = 1.f / lacc[j];
#pragma unroll
    for (int n = 0; n < 4; ++n)
      Og[(size_t)(b * Sc + q0 + wave * 16 + r4 + j) * Dc + h * HDc + n * 16 +
         cl] = (__bf16)(o[n][j] * inv);
  }
}

extern "C" void kernel_launch(void* const* d_in, const int* in_sizes, int n_in,
                              void* d_out, int out_size, void* d_ws,
                              size_t ws_size, hipStream_t stream) {
  const float* X = (const float*)d_in[0];
  const int* kpm = (const int*)d_in[1];
  const float* Wq = (const float*)d_in[2];
  const float* bq = (const float*)d_in[3];
  const float* Wk = (const float*)d_in[4];
  const float* bk = (const float*)d_in[5];
  const float* Wv = (const float*)d_in[6];
  const float* bv = (const float*)d_in[7];
  const float* Wo = (const float*)d_in[8];
  const float* bo = (const float*)d_in[9];
  float* out = (float*)d_out;

  char* w = (char*)d_ws;
  unsigned short* Xb = (unsigned short*)(w);                  // 8 MB
  unsigned short* Wqkvb = (unsigned short*)(w + (8u << 20));  // 6 MB (q,k,v)
  unsigned short* Wob = (unsigned short*)(w + (14u << 20));   // 2 MB
  unsigned short* QKVb = (unsigned short*)(w + (16u << 20));  // 24 MB
  unsigned short* Ab = (unsigned short*)(w + (40u << 20));    // 8 MB -> 48 MB

  const int MD = Bc * Sc;  // 4096
  // X (2^20 float4) + 4 weights (4 * 2^18 float4) in one launch
  cvt_all<<<dim3(8192), 256, 0, stream>>>(X, Wq, Wk, Wv, Wo, Xb, Wqkvb);

  // fused QKV projection: C is [4096][3072]; 192 blocks of 256x256
  gemm256<<<dim3(192), 512, 0, stream>>>(Xb, Wqkvb, bq, bk, bv, QKVb, Dc, LDQ);

  attn_fwd<<<dim3(1024), 256, 0, stream>>>(
      (const __bf16*)QKVb, (const __bf16*)QKVb + Dc,
      (const __bf16*)QKVb + 2 * Dc, kpm, (__bf16*)Ab);

  // output projection: 256 blocks (32/XCD)
  gemm_bt<float><<<dim3(32 * 8), 256, 0, stream>>>(
      Ab, Wob, bo, bo, bo, out, MD, Dc, Dc);
}